// Round 12
// baseline (76.307 us; speedup 1.0000x reference)
//
#include <hip/hip_runtime.h>
#include <hip/hip_bf16.h>

#define D 128          // D_IN == D_OUT
#define K2 256         // 2*D (concat width)
#define NT 64          // nodes per block (8 per wave)
#define NTHREADS 512   // 8 waves
#define AGM_LD 136     // agg row stride (bf16) -> 272B: bank-clean b64/b128

typedef __attribute__((ext_vector_type(8))) short bf16x8;  // MFMA A/B frag
typedef __attribute__((ext_vector_type(4))) float f32x4;   // MFMA C/D frag
typedef __attribute__((ext_vector_type(2))) float f32x2;

static __device__ __forceinline__ unsigned short f2bf(float f) {
    __hip_bfloat16 h = __float2bfloat16(f);   // RNE
    return *reinterpret_cast<unsigned short*>(&h);
}

// ---------------- fp8 e4m3 (OCP) encode/decode helpers ----------------
static __device__ __forceinline__ unsigned int f2q_manual(float f) {
    f = fminf(fmaxf(f, -448.f), 448.f);
    unsigned int u = __float_as_uint(f * 0x1.0p-120f);
    const unsigned int lsb = (u >> 20) & 1u;
    u += 0x7ffffu + lsb;
    return ((u >> 24) & 0x80u) | ((u >> 20) & 0x7fu);
}
static __device__ __forceinline__ float q2f_manual(unsigned int b) {
    const unsigned int bits = ((b & 0x80u) << 24) | ((b & 0x7fu) << 20);
    return __uint_as_float(bits) * 0x1.0p+120f;
}
static __device__ __forceinline__ unsigned int pack_fp8x4(float4 v) {
#if __has_builtin(__builtin_amdgcn_cvt_pk_fp8_f32)
    int lo = __builtin_amdgcn_cvt_pk_fp8_f32(v.x, v.y, 0, false);
    int q  = __builtin_amdgcn_cvt_pk_fp8_f32(v.z, v.w, lo, true);
    return (unsigned int)q;
#else
    return f2q_manual(v.x) | (f2q_manual(v.y) << 8) |
           (f2q_manual(v.z) << 16) | (f2q_manual(v.w) << 24);
#endif
}
static __device__ __forceinline__ f32x2 unpack_fp8_lo(unsigned int v) {
#if __has_builtin(__builtin_amdgcn_cvt_pk_f32_fp8)
    return __builtin_amdgcn_cvt_pk_f32_fp8((int)v, false);
#else
    f32x2 r; r[0] = q2f_manual(v & 0xffu); r[1] = q2f_manual((v >> 8) & 0xffu); return r;
#endif
}
static __device__ __forceinline__ f32x2 unpack_fp8_hi(unsigned int v) {
#if __has_builtin(__builtin_amdgcn_cvt_pk_f32_fp8)
    return __builtin_amdgcn_cvt_pk_f32_fp8((int)v, true);
#else
    f32x2 r; r[0] = q2f_manual((v >> 16) & 0xffu); r[1] = q2f_manual((v >> 24) & 0xffu); return r;
#endif
}

// ------ Kernel A: x -> fp8 table (all rows) + bf16 self rows + bf16 W ------
__global__ __launch_bounds__(256)
void convert_all(const float* __restrict__ x, const float* __restrict__ W,
                 unsigned int* __restrict__ xq4,   // 4 fp8 per uint
                 uint2* __restrict__ xbs4,         // 4 bf16 per uint2 (self rows)
                 uint2* __restrict__ wb4,          // 4 bf16 per uint2
                 long n4x, long n4s, long n4w)
{
    const long gid = (long)blockIdx.x * blockDim.x + threadIdx.x;
    const long stride = (long)gridDim.x * blockDim.x;
    for (long t = gid; t < n4x; t += stride) {
        const float4 v = reinterpret_cast<const float4*>(x)[t];
        xq4[t] = pack_fp8x4(v);
        if (t < n4s) {
            uint2 p;
            p.x = (unsigned int)f2bf(v.x) | ((unsigned int)f2bf(v.y) << 16);
            p.y = (unsigned int)f2bf(v.z) | ((unsigned int)f2bf(v.w) << 16);
            xbs4[t] = p;
        }
    }
    for (long t = gid; t < n4w; t += stride) {
        const float4 v = reinterpret_cast<const float4*>(W)[t];
        uint2 p;
        p.x = (unsigned int)f2bf(v.x) | ((unsigned int)f2bf(v.y) << 16);
        p.y = (unsigned int)f2bf(v.z) | ((unsigned int)f2bf(v.w) << 16);
        wb4[t] = p;
    }
}

// ---- Kernel B: fp8 gather + self->LDS + single-barrier split-B MFMA GEMM ----
// 8 waves; wave w gathers nodes [w*8, w*8+8), computes cols [w*16, w*16+16)
// for all 64 nodes. B slice loaded in two 4-frag halves (16 VGPRs peak) so the
// kernel fits the 64-VGPR cap of 4 blocks/CU (32 waves/CU). One barrier total.
__global__ __launch_bounds__(NTHREADS, 8)
void sage_fp8r(const unsigned char* __restrict__ xq,
               const unsigned short* __restrict__ xbs,
               const unsigned short* __restrict__ wb,
               const int* __restrict__ rp,
               const int* __restrict__ ci,
               const float* __restrict__ lb,
               const float* __restrict__ bb,
               float* __restrict__ y,
               int n_out)
{
    __shared__ unsigned short aggS[NT][AGM_LD];  // bf16 self half
    __shared__ unsigned short aggM[NT][AGM_LD];  // bf16 mean half
    __shared__ int rpls[NT + 1];
    __shared__ int cils[NT * 16];

    const int tid   = threadIdx.x;
    const int wave  = tid >> 6;                  // 0..7
    const int lane  = tid & 63;
    const int node0 = blockIdx.x * NT;
    const int nt_act = min(NT, n_out - node0);

    if (tid <= nt_act) rpls[tid] = rp[node0 + tid];
    __syncthreads();
    const int e_base = rpls[0];
    const int e_cnt  = rpls[nt_act] - e_base;
    const bool fits  = (e_cnt <= NT * 16);
    if (fits) {
        for (int i = tid; i < e_cnt; i += NTHREADS) cils[i] = ci[e_base + i];
    }
    __syncthreads();

    // ---- Phase 1: gather. Half-wave split: nsel picks node of the pair;
    //      each lane owns 4 dims -> 16 independent 4B loads per pair. ----
    const int nsel = lane >> 5;
    const int dg4  = (lane & 31) * 4;            // dim base (0,4,...,124)

    for (int p = 0; p < 4; ++p) {
        const int n0 = wave * 8 + p * 2;
        if (n0 >= nt_act) break;
        const bool has1 = (n0 + 1 < nt_act);

        const int s0 = rpls[n0] - e_base;
        const int d0 = rpls[n0 + 1] - e_base - s0;
        int s1 = s0, d1 = d0;
        if (has1) { s1 = rpls[n0 + 1] - e_base; d1 = rpls[n0 + 2] - e_base - s1; }

        const int  my_n   = n0 + nsel;
        const int  my_s   = nsel ? s1 : s0;
        const int  my_d   = nsel ? d1 : d0;
        const bool active = (nsel == 0) || has1;

        // self row copy: 32 lanes x 8B = full 256B bf16 row, coalesced
        if (active) {
            const uint2 sv = *reinterpret_cast<const uint2*>(
                &xbs[(size_t)(node0 + my_n) * D + dg4]);
            *reinterpret_cast<uint2*>(&aggS[my_n][dg4]) = sv;
        }

        f32x2 a01 = (f32x2){0.f, 0.f};
        f32x2 a23 = (f32x2){0.f, 0.f};
        if (fits && has1 && d0 == 16 && d1 == 16) {
            int idx[16];
            #pragma unroll
            for (int u = 0; u < 16; ++u) idx[u] = cils[my_s + u];
            #pragma unroll
            for (int u = 0; u < 16; ++u) {
                const unsigned int v = *reinterpret_cast<const unsigned int*>(
                    &xq[(size_t)idx[u] * D + dg4]);
                a01 += unpack_fp8_lo(v);         // v_pk_add_f32
                a23 += unpack_fp8_hi(v);
            }
        } else if (active) {
            for (int u = 0; u < my_d; ++u) {
                const int c = fits ? cils[my_s + u] : ci[e_base + my_s + u];
                const unsigned int v = *reinterpret_cast<const unsigned int*>(
                    &xq[(size_t)c * D + dg4]);
                a01 += unpack_fp8_lo(v);
                a23 += unpack_fp8_hi(v);
            }
        }
        if (active) {
            const float inv = 1.0f / (float)max(my_d, 1);
            uint2 pk;
            pk.x = (unsigned int)f2bf(a01[0] * inv) | ((unsigned int)f2bf(a01[1] * inv) << 16);
            pk.y = (unsigned int)f2bf(a23[0] * inv) | ((unsigned int)f2bf(a23[1] * inv) << 16);
            *reinterpret_cast<uint2*>(&aggM[my_n][dg4]) = pk;   // 8B, bank-clean
        }
    }

    __syncthreads();   // the ONLY barrier: publish aggS/aggM across waves

    // ---- Phase 2: MFMA GEMM, barrier-free. M=64 x N=16 x K=256 per wave.
    //      B in two 4-frag halves to keep peak VGPRs under the 64 cap. ----
    const int n15  = lane & 15;
    const int g    = lane >> 4;
    const int colb = wave * 16;

    f32x4 acc[4];
    #pragma unroll
    for (int mt = 0; mt < 4; ++mt) acc[mt] = (f32x4){0.f, 0.f, 0.f, 0.f};

    {   // K-half 1: self features (k = 0..127), A from aggS
        bf16x8 Bf[4];
        #pragma unroll
        for (int kc = 0; kc < 4; ++kc)
            Bf[kc] = *reinterpret_cast<const bf16x8*>(
                &wb[(size_t)(colb + n15) * K2 + kc * 32 + g * 8]);
        #pragma unroll
        for (int mt = 0; mt < 4; ++mt) {
            const int arow = mt * 16 + n15;
            #pragma unroll
            for (int kc = 0; kc < 4; ++kc) {
                const bf16x8 a = *reinterpret_cast<const bf16x8*>(
                    &aggS[arow][kc * 32 + g * 8]);
                acc[mt] = __builtin_amdgcn_mfma_f32_16x16x32_bf16(a, Bf[kc], acc[mt], 0, 0, 0);
            }
        }
    }
    {   // K-half 2: mean features (k = 128..255), A from aggM
        bf16x8 Bf[4];
        #pragma unroll
        for (int kc = 0; kc < 4; ++kc)
            Bf[kc] = *reinterpret_cast<const bf16x8*>(
                &wb[(size_t)(colb + n15) * K2 + 128 + kc * 32 + g * 8]);
        #pragma unroll
        for (int mt = 0; mt < 4; ++mt) {
            const int arow = mt * 16 + n15;
            #pragma unroll
            for (int kc = 0; kc < 4; ++kc) {
                const bf16x8 a = *reinterpret_cast<const bf16x8*>(
                    &aggM[arow][kc * 32 + g * 8]);
                acc[mt] = __builtin_amdgcn_mfma_f32_16x16x32_bf16(a, Bf[kc], acc[mt], 0, 0, 0);
            }
        }
    }

    // ---- Epilogue: D layout col = lane&15, row = (lane>>4)*4 + reg ----
    const int col = colb + n15;
    const float bs = lb[col] + bb[col];
    #pragma unroll
    for (int mt = 0; mt < 4; ++mt) {
        #pragma unroll
        for (int r = 0; r < 4; ++r) {
            const int row = node0 + mt * 16 + g * 4 + r;
            if (row < n_out)
                y[(size_t)row * D + col] = acc[mt][r] + bs;
        }
    }
}

// --------- Fallback (fp32 gather, barriered) if ws too small ---------
#define AGG_LDF 264
__global__ __launch_bounds__(256, 3)
void sage_fused3(const float* __restrict__ x,
                 const int* __restrict__ rp,
                 const int* __restrict__ ci,
                 const float* __restrict__ W,
                 const float* __restrict__ lb,
                 const float* __restrict__ bb,
                 float* __restrict__ y,
                 int n_out)
{
    __shared__ unsigned short aggB[NT][AGG_LDF];
    __shared__ unsigned short wtTF[D][32];
    __shared__ int rplsF[NT + 1];
    __shared__ int cilsF[NT * 16];

    const int tid   = threadIdx.x;
    const int wave  = tid >> 6;
    const int lane  = tid & 63;
    const int node0 = blockIdx.x * NT;
    const int nt_act = min(NT, n_out - node0);

    if (tid <= nt_act) rplsF[tid] = rp[node0 + tid];
    __syncthreads();
    const int e_base = rplsF[0];
    const int e_cnt  = rplsF[nt_act] - e_base;
    const bool fits  = (e_cnt <= NT * 16);
    if (fits) {
        for (int i = tid; i < e_cnt; i += 256) cilsF[i] = ci[e_base + i];
    }
    __syncthreads();

    for (int t = 0; t < 16; ++t) {
        const int nn = wave * 16 + t;
        if (nn >= nt_act) break;
        const int node = node0 + nn;
        const float2 self =
            *reinterpret_cast<const float2*>(&x[(size_t)node * D + lane * 2]);
        const int s  = rplsF[nn] - e_base;
        const int dg = rplsF[nn + 1] - e_base - s;
        float ax = 0.f, ay = 0.f;
        for (int u = 0; u < dg; ++u) {
            const int c = fits ? cilsF[s + u] : ci[e_base + s + u];
            const float2 v = *reinterpret_cast<const float2*>(
                &x[(size_t)c * D + lane * 2]);
            ax += v.x; ay += v.y;
        }
        const float inv = 1.0f / (float)max(dg, 1);
        *reinterpret_cast<unsigned int*>(&aggB[nn][lane * 2]) =
            (unsigned int)f2bf(self.x) | ((unsigned int)f2bf(self.y) << 16);
        *reinterpret_cast<unsigned int*>(&aggB[nn][D + lane * 2]) =
            (unsigned int)f2bf(ax * inv) | ((unsigned int)f2bf(ay * inv) << 16);
    }

    const int n15 = lane & 15;
    const int g   = lane >> 4;
    f32x4 acc[8];
    #pragma unroll
    for (int f = 0; f < 8; ++f) acc[f] = (f32x4){0.f, 0.f, 0.f, 0.f};

    for (int k0 = 0; k0 < K2; k0 += 32) {
        #pragma unroll
        for (int j = 0; j < 4; ++j) {
            const int idx = j * 256 + tid;
            const int o   = idx >> 3;
            const int c   = idx & 7;
            const float4 w = *reinterpret_cast<const float4*>(
                &W[(size_t)o * K2 + k0 + c * 4]);
            const unsigned int lo = (unsigned int)f2bf(w.x) | ((unsigned int)f2bf(w.y) << 16);
            const unsigned int hi = (unsigned int)f2bf(w.z) | ((unsigned int)f2bf(w.w) << 16);
            *reinterpret_cast<uint2*>(&wtTF[o][c * 4]) = make_uint2(lo, hi);
        }
        __syncthreads();
        const bf16x8 a = *reinterpret_cast<const bf16x8*>(
            &aggB[wave * 16 + n15][k0 + g * 8]);
        #pragma unroll
        for (int f = 0; f < 8; ++f) {
            const bf16x8 b = *reinterpret_cast<const bf16x8*>(&wtTF[f * 16 + n15][g * 8]);
            acc[f] = __builtin_amdgcn_mfma_f32_16x16x32_bf16(a, b, acc[f], 0, 0, 0);
        }
        __syncthreads();
    }

    const int mbase = node0 + wave * 16 + g * 4;
    #pragma unroll
    for (int f = 0; f < 8; ++f) {
        const int col  = f * 16 + n15;
        const float bs = lb[col] + bb[col];
        #pragma unroll
        for (int r = 0; r < 4; ++r) {
            const int row = mbase + r;
            if (row < n_out)
                y[(size_t)row * D + col] = acc[f][r] + bs;
        }
    }
}

extern "C" void kernel_launch(void* const* d_in, const int* in_sizes, int n_in,
                              void* d_out, int out_size, void* d_ws, size_t ws_size,
                              hipStream_t stream)
{
    const float* x  = (const float*)d_in[0];
    const int*   rp = (const int*)d_in[1];
    const int*   ci = (const int*)d_in[2];
    // d_in[3] = sample_count (scalar) — degree comes from row_ptr
    const float* W  = (const float*)d_in[4];
    const float* lb = (const float*)d_in[5];
    const float* bb = (const float*)d_in[6];
    float* y = (float*)d_out;

    const int n_out = in_sizes[1] - 1;
    const int grid  = (n_out + NT - 1) / NT;

    const size_t n_x = (size_t)in_sizes[0];
    const size_t n_w = (size_t)in_sizes[4];
    const size_t xq_bytes  = n_x;                         // fp8: 1 B/elem
    const size_t xbs_bytes = (size_t)n_out * D * 2;       // bf16 self rows
    const size_t wb_bytes  = n_w * 2;
    const size_t need = xq_bytes + xbs_bytes + wb_bytes;

    if (ws_size >= need) {
        unsigned char*  xq  = (unsigned char*)d_ws;
        unsigned short* xbs = (unsigned short*)((char*)d_ws + xq_bytes);
        unsigned short* wb  = (unsigned short*)((char*)d_ws + xq_bytes + xbs_bytes);
        hipLaunchKernelGGL(convert_all, dim3(2048), dim3(256), 0, stream,
                           x, W, (unsigned int*)xq, (uint2*)xbs, (uint2*)wb,
                           (long)(n_x >> 2), (long)(((size_t)n_out * D) >> 2),
                           (long)(n_w >> 2));
        hipLaunchKernelGGL(sage_fp8r, dim3(grid), dim3(NTHREADS), 0, stream,
                           xq, xbs, wb, rp, ci, lb, bb, y, n_out);
    } else {
        hipLaunchKernelGGL(sage_fused3, dim3(grid), dim3(256), 0, stream,
                           x, rp, ci, W, lb, bb, y, n_out);
    }
}